// Round 2
// baseline (415.067 us; speedup 1.0000x reference)
//
#include <hip/hip_runtime.h>
#include <hip/hip_bf16.h>
#include <hip/hip_fp16.h>

#define IN_F 4096
#define OUT_F 16384
#define TOKENS 64

#define NT 32                    // channels per block
#define KHALF 2048               // K per wave-pair half
#define NKB (KHALF / 32)         // 64 k-blocks of 32 per wave
#define BLOCK 256

typedef __attribute__((ext_vector_type(8))) short bf16x8;
typedef __attribute__((ext_vector_type(8))) unsigned short u16x8;
typedef __attribute__((ext_vector_type(4))) float f32x4;
typedef __attribute__((ext_vector_type(4))) int i32x4;

enum { F_BF16 = 0, F_FP16 = 1, F_FP32 = 2 };

__device__ __forceinline__ float dec_bf16(unsigned short h) {
    return __uint_as_float(((unsigned)h) << 16);
}
__device__ __forceinline__ float dec_fp16(unsigned short h) {
    __half_raw hr; hr.x = h;
    return __half2float(__half(hr));
}
__device__ __forceinline__ unsigned short enc_bf16_rne(float f) {
    unsigned u = __float_as_uint(f);
    u += 0x7FFFu + ((u >> 16) & 1u);
    return (unsigned short)(u >> 16);
}

// Wave-uniform format detection (verified passing — keep verbatim).
__device__ __forceinline__ int detect_fmt16(const void* p, int lane, float lo, float hi) {
    unsigned short h = ((const unsigned short*)p)[lane];
    float vb = fabsf(dec_bf16(h));
    float vh = fabsf(dec_fp16(h));
    int cb = __popcll(__ballot(vb > lo && vb < hi));
    int ch = __popcll(__ballot(vh > lo && vh < hi));
    return (cb >= 56) ? F_BF16 : (ch >= 56) ? F_FP16 : F_FP32;
}
__device__ __forceinline__ int detect_wint(const int* w, int lane) {
    int v = w[lane];
    int ci = __popcll(__ballot(v >= -127 && v <= 127));
    return (ci >= 56) ? 1 : 0;
}

// ---------------- pre-kernel: x -> bf16 into workspace ----------------
__global__ __launch_bounds__(256) void prep_x(const void* __restrict__ xv,
                                              unsigned short* __restrict__ xbf) {
    const int tid  = blockIdx.x * 256 + threadIdx.x;  // 16384 threads, 16 elem each
    const int lane = threadIdx.x & 63;
    const int xf = detect_fmt16(xv, lane, 9.7e-4f, 64.0f);

    if (xf == F_BF16) {
        u16x8 a = ((const u16x8*)xv)[tid * 2];
        u16x8 b = ((const u16x8*)xv)[tid * 2 + 1];
        ((u16x8*)xbf)[tid * 2]     = a;
        ((u16x8*)xbf)[tid * 2 + 1] = b;
    } else if (xf == F_FP32) {
        u16x8 o[2];
        #pragma unroll
        for (int half = 0; half < 2; ++half) {
            f32x4 v0 = ((const f32x4*)xv)[tid * 4 + half * 2];
            f32x4 v1 = ((const f32x4*)xv)[tid * 4 + half * 2 + 1];
            #pragma unroll
            for (int j = 0; j < 4; ++j) {
                o[half][j]     = enc_bf16_rne(v0[j]);
                o[half][j + 4] = enc_bf16_rne(v1[j]);
            }
        }
        ((u16x8*)xbf)[tid * 2]     = o[0];
        ((u16x8*)xbf)[tid * 2 + 1] = o[1];
    } else { // F_FP16
        #pragma unroll
        for (int half = 0; half < 2; ++half) {
            u16x8 v = ((const u16x8*)xv)[tid * 2 + half];
            u16x8 o;
            #pragma unroll
            for (int j = 0; j < 8; ++j) o[j] = enc_bf16_rne(dec_fp16(v[j]));
            ((u16x8*)xbf)[tid * 2 + half] = o;
        }
    }
}

// ---------------- main kernel: direct global->VGPR weight streaming ----------------
// Weights have ZERO cross-lane/cross-wave reuse -> LDS staging was a pure
// layout round-trip + barrier coupling. Each lane loads its own 8 consecutive
// int32 (two dwordx4) per k-block; per wave that's 16 rows x 128 contiguous
// bytes -> fully-consumed cache lines. No __syncthreads in the main loop.
template <int WINT>
__device__ __forceinline__ void kblock_compute(const int* __restrict__ wrow,
                                               const short* __restrict__ xrow,
                                               int kb, f32x4 acc[4]) {
    i32x4 b0 = *(const i32x4*)(wrow + kb * 32);
    i32x4 b1 = *(const i32x4*)(wrow + kb * 32 + 4);
    bf16x8 a0 = *(const bf16x8*)(xrow + kb * 32);
    bf16x8 a1 = *(const bf16x8*)(xrow + kb * 32 + 16 * IN_F);
    bf16x8 a2 = *(const bf16x8*)(xrow + kb * 32 + 32 * IN_F);
    bf16x8 a3 = *(const bf16x8*)(xrow + kb * 32 + 48 * IN_F);
    bf16x8 bfrag;
    #pragma unroll
    for (int j = 0; j < 4; ++j) {
        unsigned f0 = WINT ? __float_as_uint((float)b0[j]) : (unsigned)b0[j];
        unsigned f1 = WINT ? __float_as_uint((float)b1[j]) : (unsigned)b1[j];
        bfrag[j]     = (short)(f0 >> 16);   // int8-valued -> bf16 exact
        bfrag[j + 4] = (short)(f1 >> 16);
    }
    acc[0] = __builtin_amdgcn_mfma_f32_16x16x32_bf16(a0, bfrag, acc[0], 0, 0, 0);
    acc[1] = __builtin_amdgcn_mfma_f32_16x16x32_bf16(a1, bfrag, acc[1], 0, 0, 0);
    acc[2] = __builtin_amdgcn_mfma_f32_16x16x32_bf16(a2, bfrag, acc[2], 0, 0, 0);
    acc[3] = __builtin_amdgcn_mfma_f32_16x16x32_bf16(a3, bfrag, acc[3], 0, 0, 0);
}

__global__ __launch_bounds__(BLOCK, 2) void w8a16_main(
    const void* __restrict__ xv_orig, const int* __restrict__ w,
    const void* __restrict__ sv, const void* __restrict__ bv,
    void* __restrict__ yv, const unsigned short* __restrict__ xbf) {

    __shared__ float red[2048];   // 8 KB: cross-half reduce only

    const int tid  = threadIdx.x;
    const int wv   = tid >> 6;
    const int lane = tid & 63;
    const int ln   = lane & 15;
    const int kq   = lane >> 4;
    const int h    = wv >> 1;        // K-half this wave computes
    const int wl   = wv & 1;         // which 16-channel group
    const int n0   = blockIdx.x * NT;

    const int xf = detect_fmt16(xv_orig, lane, 9.7e-4f, 64.0f);
    const int sf = detect_fmt16(sv, lane, 1.0e-4f, 0.25f);
    const int wi = detect_wint(w, lane);

    const int row = 16 * wl + ln;    // block-local output channel
    // Per-lane stream bases (64-bit safe; byte offsets < 4 GB but keep size_t).
    const int*   wrow = w + (size_t)(n0 + row) * IN_F + h * KHALF + kq * 8;
    const short* xrow = (const short*)xbf + (size_t)ln * IN_F + h * KHALF + kq * 8;

    f32x4 acc[4] = {};
    if (wi) {
        #pragma unroll 4
        for (int kb = 0; kb < NKB; ++kb) kblock_compute<1>(wrow, xrow, kb, acc);
    } else {
        #pragma unroll 4
        for (int kb = 0; kb < NKB; ++kb) kblock_compute<0>(wrow, xrow, kb, acc);
    }

    // --- cross-half reduce through LDS ---
    if (h == 1) {
        #pragma unroll
        for (int i = 0; i < 4; ++i)
            #pragma unroll
            for (int r2 = 0; r2 < 4; ++r2)
                red[(wl * 64 + lane) * 16 + i * 4 + r2] = acc[i][r2];
    }
    __syncthreads();
    if (h == 0) {
        #pragma unroll
        for (int i = 0; i < 4; ++i)
            #pragma unroll
            for (int r2 = 0; r2 < 4; ++r2)
                acc[i][r2] += red[(wl * 64 + lane) * 16 + i * 4 + r2];

        const int n = n0 + row;
        float scale, bias;
        if (sf == F_FP32) {
            scale = ((const float*)sv)[n];
            bias  = ((const float*)bv)[n];
        } else if (sf == F_BF16) {
            scale = dec_bf16(((const unsigned short*)sv)[n]);
            bias  = dec_bf16(((const unsigned short*)bv)[n]);
        } else {
            scale = dec_fp16(((const unsigned short*)sv)[n]);
            bias  = dec_fp16(((const unsigned short*)bv)[n]);
        }

        // D layout (m89-verified): col = ln (= n), row m = 16*tile + kq*4 + reg
        #pragma unroll
        for (int i = 0; i < 4; ++i) {
            #pragma unroll
            for (int r2 = 0; r2 < 4; ++r2) {
                const int    m   = 16 * i + kq * 4 + r2;
                const float  val = acc[i][r2] * scale + bias;
                const size_t o   = (size_t)m * OUT_F + n;
                if (xf == F_FP32)      ((float*)yv)[o] = val;
                else if (xf == F_BF16) ((unsigned short*)yv)[o] = enc_bf16_rne(val);
                else                   ((__half*)yv)[o] = __float2half(val);
            }
        }
    }
}

extern "C" void kernel_launch(void* const* d_in, const int* in_sizes, int n_in,
                              void* d_out, int out_size, void* d_ws, size_t ws_size,
                              hipStream_t stream) {
    unsigned short* xbf = (unsigned short*)d_ws;   // 512 KB: x as bf16
    prep_x<<<64, 256, 0, stream>>>(d_in[0], xbf);
    w8a16_main<<<OUT_F / NT, BLOCK, 0, stream>>>(d_in[0], (const int*)d_in[1],
                                                 d_in[2], d_in[3], d_out, xbf);
}

// Round 3
// 382.079 us; speedup vs baseline: 1.0863x; 1.0863x over previous
//
#include <hip/hip_runtime.h>
#include <hip/hip_bf16.h>
#include <hip/hip_fp16.h>

#define IN_F 4096
#define OUT_F 16384
#define TOKENS 64

#define NT 32                    // channels per block
#define KT 128                   // k per tile
#define KHALF 2048               // K per wave-pair half
#define NTILES 16                // KHALF / KT
#define TILE_BYTES (NT * KT * 4) // 16 KB per half-tile
#define BLOCK 256

typedef __attribute__((ext_vector_type(8))) short bf16x8;
typedef __attribute__((ext_vector_type(8))) unsigned short u16x8;
typedef __attribute__((ext_vector_type(4))) float f32x4;
typedef __attribute__((ext_vector_type(4))) int i32x4;

enum { F_BF16 = 0, F_FP16 = 1, F_FP32 = 2 };

__device__ __forceinline__ float dec_bf16(unsigned short h) {
    return __uint_as_float(((unsigned)h) << 16);
}
__device__ __forceinline__ float dec_fp16(unsigned short h) {
    __half_raw hr; hr.x = h;
    return __half2float(__half(hr));
}
__device__ __forceinline__ unsigned short enc_bf16_rne(float f) {
    unsigned u = __float_as_uint(f);
    u += 0x7FFFu + ((u >> 16) & 1u);
    return (unsigned short)(u >> 16);
}

// Wave-uniform format detection (verified passing in round 2 — keep verbatim).
__device__ __forceinline__ int detect_fmt16(const void* p, int lane, float lo, float hi) {
    unsigned short h = ((const unsigned short*)p)[lane];
    float vb = fabsf(dec_bf16(h));
    float vh = fabsf(dec_fp16(h));
    int cb = __popcll(__ballot(vb > lo && vb < hi));
    int ch = __popcll(__ballot(vh > lo && vh < hi));
    return (cb >= 56) ? F_BF16 : (ch >= 56) ? F_FP16 : F_FP32;
}
__device__ __forceinline__ int detect_wint(const int* w, int lane) {
    int v = w[lane];
    int ci = __popcll(__ballot(v >= -127 && v <= 127));
    return (ci >= 56) ? 1 : 0;
}

// ---------------- pre-kernel: x -> bf16 into workspace ----------------
__global__ __launch_bounds__(256) void prep_x(const void* __restrict__ xv,
                                              unsigned short* __restrict__ xbf) {
    const int tid  = blockIdx.x * 256 + threadIdx.x;  // 16384 threads, 16 elem each
    const int lane = threadIdx.x & 63;
    const int xf = detect_fmt16(xv, lane, 9.7e-4f, 64.0f);

    if (xf == F_BF16) {
        u16x8 a = ((const u16x8*)xv)[tid * 2];
        u16x8 b = ((const u16x8*)xv)[tid * 2 + 1];
        ((u16x8*)xbf)[tid * 2]     = a;
        ((u16x8*)xbf)[tid * 2 + 1] = b;
    } else if (xf == F_FP32) {
        u16x8 o[2];
        #pragma unroll
        for (int half = 0; half < 2; ++half) {
            f32x4 v0 = ((const f32x4*)xv)[tid * 4 + half * 2];
            f32x4 v1 = ((const f32x4*)xv)[tid * 4 + half * 2 + 1];
            #pragma unroll
            for (int j = 0; j < 4; ++j) {
                o[half][j]     = enc_bf16_rne(v0[j]);
                o[half][j + 4] = enc_bf16_rne(v1[j]);
            }
        }
        ((u16x8*)xbf)[tid * 2]     = o[0];
        ((u16x8*)xbf)[tid * 2 + 1] = o[1];
    } else { // F_FP16
        #pragma unroll
        for (int half = 0; half < 2; ++half) {
            u16x8 v = ((const u16x8*)xv)[tid * 2 + half];
            u16x8 o;
            #pragma unroll
            for (int j = 0; j < 8; ++j) o[j] = enc_bf16_rne(dec_fp16(v[j]));
            ((u16x8*)xbf)[tid * 2 + half] = o;
        }
    }
}

// ---------------- main kernel ----------------
template <int WINT>
__device__ __forceinline__ void tile_compute(const char* __restrict__ buf,
                                             const unsigned short* __restrict__ xbf,
                                             int kbase, int ln, int kq, int row,
                                             f32x4 acc[4]) {
    const char*  bufb = buf + row * 512;   // row stride = KT*4 = 512 B
    const short* xs   = (const short*)xbf;
    #pragma unroll
    for (int kt = 0; kt < 4; ++kt) {
        const int c0 = kt * 8 + 2 * kq;    // 16B-chunk index, XOR-16 swizzled by row&15 (== ln)
        i32x4 b0 = *(const i32x4*)(bufb + ((c0)     ^ ln) * 16);
        i32x4 b1 = *(const i32x4*)(bufb + ((c0 + 1) ^ ln) * 16);
        bf16x8 bfrag;
        #pragma unroll
        for (int j = 0; j < 4; ++j) {
            unsigned f0 = WINT ? __float_as_uint((float)b0[j]) : (unsigned)b0[j];
            unsigned f1 = WINT ? __float_as_uint((float)b1[j]) : (unsigned)b1[j];
            bfrag[j]     = (short)(f0 >> 16);   // int8-valued -> bf16 exact
            bfrag[j + 4] = (short)(f1 >> 16);
        }
        const int kk = kbase + kt * 32 + kq * 8;
        bf16x8 a0 = *(const bf16x8*)(xs + (size_t)(ln     ) * IN_F + kk);
        bf16x8 a1 = *(const bf16x8*)(xs + (size_t)(ln + 16) * IN_F + kk);
        bf16x8 a2 = *(const bf16x8*)(xs + (size_t)(ln + 32) * IN_F + kk);
        bf16x8 a3 = *(const bf16x8*)(xs + (size_t)(ln + 48) * IN_F + kk);
        acc[0] = __builtin_amdgcn_mfma_f32_16x16x32_bf16(a0, bfrag, acc[0], 0, 0, 0);
        acc[1] = __builtin_amdgcn_mfma_f32_16x16x32_bf16(a1, bfrag, acc[1], 0, 0, 0);
        acc[2] = __builtin_amdgcn_mfma_f32_16x16x32_bf16(a2, bfrag, acc[2], 0, 0, 0);
        acc[3] = __builtin_amdgcn_mfma_f32_16x16x32_bf16(a3, bfrag, acc[3], 0, 0, 0);
    }
}

__global__ __launch_bounds__(BLOCK, 2) void w8a16_main(
    const void* __restrict__ xv_orig, const int* __restrict__ w,
    const void* __restrict__ sv, const void* __restrict__ bv,
    void* __restrict__ yv, const unsigned short* __restrict__ xbf) {

    __shared__ alignas(16) char lds[2][2][TILE_BYTES];   // [half][dbuf][16KB] = 64 KB

    const int tid  = threadIdx.x;
    const int wv   = tid >> 6;
    const int lane = tid & 63;
    const int ln   = lane & 15;
    const int kq   = lane >> 4;
    const int h    = wv >> 1;        // K-half this wave computes
    const int wl   = wv & 1;         // which 16-channel group
    const int n0   = blockIdx.x * NT;

    const int xf = detect_fmt16(xv_orig, lane, 9.7e-4f, 64.0f);
    const int sf = detect_fmt16(sv, lane, 1.0e-4f, 0.25f);
    const int wi = detect_wint(w, lane);

    // --- async staging: threads 0-127 stage half 0, 128-255 stage half 1 ---
    const int th   = tid >> 7;
    const int t127 = tid & 127;
    auto stage = [&](int tile, int dbuf) {
        #pragma unroll
        for (int j = 0; j < 8; ++j) {
            const int idx = j * 128 + t127;     // chunk slot in tile
            const int r   = idx >> 5;           // row 0..31
            const int c   = idx & 31;           // stored position
            const int cg  = c ^ (r & 15);       // global chunk (self-inverse swizzle)
            const int* g = w + (size_t)(n0 + r) * IN_F + th * KHALF + tile * KT + cg * 4;
            char* l = &lds[th][dbuf][idx * 16];
            __builtin_amdgcn_global_load_lds(
                (const __attribute__((address_space(1))) unsigned int*)g,
                (__attribute__((address_space(3))) unsigned int*)l, 16, 0, 0);
        }
    };

    f32x4 acc[4] = {};
    const int row = 16 * wl + ln;               // tile-local B row (row & 15 == ln)

    stage(0, 0);
    __syncthreads();
    for (int t = 0; t < NTILES; ++t) {
        if (t + 1 < NTILES) stage(t + 1, (t + 1) & 1);
        const char* buf   = &lds[h][t & 1][0];
        const int   kbase = h * KHALF + t * KT;
        if (wi) tile_compute<1>(buf, xbf, kbase, ln, kq, row, acc);
        else    tile_compute<0>(buf, xbf, kbase, ln, kq, row, acc);
        __syncthreads();
    }

    // --- cross-half reduce through LDS (reuse tile buffers) ---
    float* red = (float*)&lds[0][0][0];
    if (h == 1) {
        #pragma unroll
        for (int i = 0; i < 4; ++i)
            #pragma unroll
            for (int r2 = 0; r2 < 4; ++r2)
                red[(wl * 64 + lane) * 16 + i * 4 + r2] = acc[i][r2];
    }
    __syncthreads();
    if (h == 0) {
        #pragma unroll
        for (int i = 0; i < 4; ++i)
            #pragma unroll
            for (int r2 = 0; r2 < 4; ++r2)
                acc[i][r2] += red[(wl * 64 + lane) * 16 + i * 4 + r2];

        const int n = n0 + row;
        float scale, bias;
        if (sf == F_FP32) {
            scale = ((const float*)sv)[n];
            bias  = ((const float*)bv)[n];
        } else if (sf == F_BF16) {
            scale = dec_bf16(((const unsigned short*)sv)[n]);
            bias  = dec_bf16(((const unsigned short*)bv)[n]);
        } else {
            scale = dec_fp16(((const unsigned short*)sv)[n]);
            bias  = dec_fp16(((const unsigned short*)bv)[n]);
        }

        // D layout (m89-verified): col = ln (= n), row m = 16*tile + kq*4 + reg
        #pragma unroll
        for (int i = 0; i < 4; ++i) {
            #pragma unroll
            for (int r2 = 0; r2 < 4; ++r2) {
                const int    m   = 16 * i + kq * 4 + r2;
                const float  val = acc[i][r2] * scale + bias;
                const size_t o   = (size_t)m * OUT_F + n;
                if (xf == F_FP32)      ((float*)yv)[o] = val;
                else if (xf == F_BF16) ((unsigned short*)yv)[o] = enc_bf16_rne(val);
                else                   ((__half*)yv)[o] = __float2half(val);
            }
        }
    }
}

extern "C" void kernel_launch(void* const* d_in, const int* in_sizes, int n_in,
                              void* d_out, int out_size, void* d_ws, size_t ws_size,
                              hipStream_t stream) {
    unsigned short* xbf = (unsigned short*)d_ws;   // 512 KB: x as bf16
    prep_x<<<64, 256, 0, stream>>>(d_in[0], xbf);
    w8a16_main<<<OUT_F / NT, BLOCK, 0, stream>>>(d_in[0], (const int*)d_in[1],
                                                 d_in[2], d_in[3], d_out, xbf);
}

// Round 4
// 378.991 us; speedup vs baseline: 1.0952x; 1.0081x over previous
//
#include <hip/hip_runtime.h>
#include <hip/hip_bf16.h>
#include <hip/hip_fp16.h>

#define IN_F 4096
#define OUT_F 16384
#define TOKENS 64

#define NT 32                    // channels per block
#define KT 64                    // k per tile
#define KHALF 2048               // K per wave-pair half
#define NTILES 32                // KHALF / KT
#define NBUF 3                   // triple buffer: stage(t+2) while computing t
#define TILE_BYTES (NT * KT * 4) // 8 KB per half-tile; total LDS 48 KB -> 2 blocks/CU
#define BLOCK 256

typedef __attribute__((ext_vector_type(8))) short bf16x8;
typedef __attribute__((ext_vector_type(8))) unsigned short u16x8;
typedef __attribute__((ext_vector_type(4))) float f32x4;
typedef __attribute__((ext_vector_type(4))) int i32x4;

enum { F_BF16 = 0, F_FP16 = 1, F_FP32 = 2 };

__device__ __forceinline__ float dec_bf16(unsigned short h) {
    return __uint_as_float(((unsigned)h) << 16);
}
__device__ __forceinline__ float dec_fp16(unsigned short h) {
    __half_raw hr; hr.x = h;
    return __half2float(__half(hr));
}
__device__ __forceinline__ unsigned short enc_bf16_rne(float f) {
    unsigned u = __float_as_uint(f);
    u += 0x7FFFu + ((u >> 16) & 1u);
    return (unsigned short)(u >> 16);
}

// Wave-uniform format detection (verified passing — keep verbatim).
__device__ __forceinline__ int detect_fmt16(const void* p, int lane, float lo, float hi) {
    unsigned short h = ((const unsigned short*)p)[lane];
    float vb = fabsf(dec_bf16(h));
    float vh = fabsf(dec_fp16(h));
    int cb = __popcll(__ballot(vb > lo && vb < hi));
    int ch = __popcll(__ballot(vh > lo && vh < hi));
    return (cb >= 56) ? F_BF16 : (ch >= 56) ? F_FP16 : F_FP32;
}
__device__ __forceinline__ int detect_wint(const int* w, int lane) {
    int v = w[lane];
    int ci = __popcll(__ballot(v >= -127 && v <= 127));
    return (ci >= 56) ? 1 : 0;
}

// ---------------- pre-kernel: x -> bf16 into workspace ----------------
__global__ __launch_bounds__(256) void prep_x(const void* __restrict__ xv,
                                              unsigned short* __restrict__ xbf) {
    const int tid  = blockIdx.x * 256 + threadIdx.x;  // 16384 threads, 16 elem each
    const int lane = threadIdx.x & 63;
    const int xf = detect_fmt16(xv, lane, 9.7e-4f, 64.0f);

    if (xf == F_BF16) {
        u16x8 a = ((const u16x8*)xv)[tid * 2];
        u16x8 b = ((const u16x8*)xv)[tid * 2 + 1];
        ((u16x8*)xbf)[tid * 2]     = a;
        ((u16x8*)xbf)[tid * 2 + 1] = b;
    } else if (xf == F_FP32) {
        u16x8 o[2];
        #pragma unroll
        for (int half = 0; half < 2; ++half) {
            f32x4 v0 = ((const f32x4*)xv)[tid * 4 + half * 2];
            f32x4 v1 = ((const f32x4*)xv)[tid * 4 + half * 2 + 1];
            #pragma unroll
            for (int j = 0; j < 4; ++j) {
                o[half][j]     = enc_bf16_rne(v0[j]);
                o[half][j + 4] = enc_bf16_rne(v1[j]);
            }
        }
        ((u16x8*)xbf)[tid * 2]     = o[0];
        ((u16x8*)xbf)[tid * 2 + 1] = o[1];
    } else { // F_FP16
        #pragma unroll
        for (int half = 0; half < 2; ++half) {
            u16x8 v = ((const u16x8*)xv)[tid * 2 + half];
            u16x8 o;
            #pragma unroll
            for (int j = 0; j < 8; ++j) o[j] = enc_bf16_rne(dec_fp16(v[j]));
            ((u16x8*)xbf)[tid * 2 + half] = o;
        }
    }
}

// ---------------- main kernel ----------------
// Depth-2 pipeline with FIFO-correct counted vmcnt:
//   per tile t:  issue x(t+1)->regs; s_waitcnt vmcnt(12)  [drains x(t)+stage(t),
//   keeps stage(t+1)+x(t+1)=12 in flight]; s_barrier; issue stage(t+2); compute(t)
//   from LDS + x-registers only (NO global loads in compute -> no compiler vmcnt
//   waits that would force-drain the prefetch, which is what killed round 1).
template <int WINT>
__device__ __forceinline__ void tile_compute(const char* __restrict__ buf,
                                             const bf16x8 (&xr)[8],
                                             int ln, int kq, int row,
                                             f32x4 acc[4]) {
    const char* bufb = buf + row * (KT * 4);   // row stride = 256 B = 16 chunks
    #pragma unroll
    for (int kt = 0; kt < 2; ++kt) {
        const int c0 = kt * 8 + 2 * kq;        // chunk index, XOR-16 swizzle by row&15==ln
        i32x4 b0 = *(const i32x4*)(bufb + ((c0)     ^ ln) * 16);
        i32x4 b1 = *(const i32x4*)(bufb + ((c0 + 1) ^ ln) * 16);
        bf16x8 bfrag;
        #pragma unroll
        for (int j = 0; j < 4; ++j) {
            unsigned f0 = WINT ? __float_as_uint((float)b0[j]) : (unsigned)b0[j];
            unsigned f1 = WINT ? __float_as_uint((float)b1[j]) : (unsigned)b1[j];
            bfrag[j]     = (short)(f0 >> 16);   // int8-valued -> bf16 exact
            bfrag[j + 4] = (short)(f1 >> 16);
        }
        acc[0] = __builtin_amdgcn_mfma_f32_16x16x32_bf16(xr[kt * 4 + 0], bfrag, acc[0], 0, 0, 0);
        acc[1] = __builtin_amdgcn_mfma_f32_16x16x32_bf16(xr[kt * 4 + 1], bfrag, acc[1], 0, 0, 0);
        acc[2] = __builtin_amdgcn_mfma_f32_16x16x32_bf16(xr[kt * 4 + 2], bfrag, acc[2], 0, 0, 0);
        acc[3] = __builtin_amdgcn_mfma_f32_16x16x32_bf16(xr[kt * 4 + 3], bfrag, acc[3], 0, 0, 0);
    }
}

__global__ __launch_bounds__(BLOCK, 2) void w8a16_main(
    const void* __restrict__ xv_orig, const int* __restrict__ w,
    const void* __restrict__ sv, const void* __restrict__ bv,
    void* __restrict__ yv, const unsigned short* __restrict__ xbf) {

    __shared__ alignas(16) char lds[2][NBUF][TILE_BYTES];   // 48 KB

    const int tid  = threadIdx.x;
    const int wv   = tid >> 6;
    const int lane = tid & 63;
    const int ln   = lane & 15;
    const int kq   = lane >> 4;
    const int h    = wv >> 1;        // K-half this wave computes
    const int wl   = wv & 1;         // which 16-channel group
    const int n0   = blockIdx.x * NT;

    const int xf = detect_fmt16(xv_orig, lane, 9.7e-4f, 64.0f);
    const int sf = detect_fmt16(sv, lane, 1.0e-4f, 0.25f);
    const int wi = detect_wint(w, lane);

    // --- async staging: threads 0-127 stage half 0, 128-255 stage half 1 ---
    // 4 x global_load_lds(16B) per thread per stage.
    const int th   = tid >> 7;
    const int t127 = tid & 127;
    auto stage = [&](int tile, int dbuf) {
        #pragma unroll
        for (int j = 0; j < 4; ++j) {
            const int idx = j * 128 + t127;     // chunk slot (0..511)
            const int r   = idx >> 4;           // row 0..31 (16 chunks/row)
            const int c   = idx & 15;
            const int cg  = c ^ (r & 15);       // self-inverse swizzle
            const int* g = w + (size_t)(n0 + r) * IN_F + th * KHALF + tile * KT + cg * 4;
            char* l = &lds[th][dbuf][idx * 16];
            __builtin_amdgcn_global_load_lds(
                (const __attribute__((address_space(1))) unsigned int*)g,
                (__attribute__((address_space(3))) unsigned int*)l, 16, 0, 0);
        }
    };

    // --- x fragment loads (global -> regs), 8 x 16B per tile ---
    const short* xs = (const short*)xbf;
    auto load_x = [&](int tile, bf16x8 (&xr)[8]) {
        const int kk = h * KHALF + tile * KT + kq * 8;
        #pragma unroll
        for (int kt = 0; kt < 2; ++kt)
            #pragma unroll
            for (int r = 0; r < 4; ++r)
                xr[kt * 4 + r] = *(const bf16x8*)(xs + (size_t)(ln + 16 * r) * IN_F + kk + kt * 32);
    };

    f32x4 acc[4] = {};
    const int row = 16 * wl + ln;               // tile-local B row (row & 15 == ln)

    bf16x8 xA[8], xB[8];

    // prologue: issue order matters for FIFO vmcnt accounting
    stage(0, 0);        // 4 loads
    load_x(0, xA);      // 8 loads
    stage(1, 1);        // 4 loads

    auto body = [&](int t, const bf16x8 (&xc)[8], bf16x8 (&xn)[8]) {
        if (t + 1 < NTILES) {
            load_x(t + 1, xn);                     // newest 8: stay in flight
            // drain 8 oldest = {x(t), stage(t)}; keep stage(t+1)[4]+x(t+1)[8]
            asm volatile("s_waitcnt vmcnt(12)" ::: "memory");
        } else {
            asm volatile("s_waitcnt vmcnt(0)" ::: "memory");
        }
        __builtin_amdgcn_s_barrier();              // all threads' stage(t) visible
        if (t + 2 < NTILES) stage(t + 2, (t + 2) % 3);  // target's readers retired
        const char* buf = &lds[h][t % 3][0];
        if (wi) tile_compute<1>(buf, xc, ln, kq, row, acc);
        else    tile_compute<0>(buf, xc, ln, kq, row, acc);
    };

    for (int t = 0; t < NTILES; t += 2) {   // NTILES even; named x bufs (rule #20)
        body(t,     xA, xB);
        body(t + 1, xB, xA);
    }

    // --- cross-half reduce through LDS (red = lds[0][0], disjoint from buf[1/2]) ---
    float* red = (float*)&lds[0][0][0];
    if (h == 1) {
        #pragma unroll
        for (int i = 0; i < 4; ++i)
            #pragma unroll
            for (int r2 = 0; r2 < 4; ++r2)
                red[(wl * 64 + lane) * 16 + i * 4 + r2] = acc[i][r2];
    }
    __syncthreads();
    if (h == 0) {
        #pragma unroll
        for (int i = 0; i < 4; ++i)
            #pragma unroll
            for (int r2 = 0; r2 < 4; ++r2)
                acc[i][r2] += red[(wl * 64 + lane) * 16 + i * 4 + r2];

        const int n = n0 + row;
        float scale, bias;
        if (sf == F_FP32) {
            scale = ((const float*)sv)[n];
            bias  = ((const float*)bv)[n];
        } else if (sf == F_BF16) {
            scale = dec_bf16(((const unsigned short*)sv)[n]);
            bias  = dec_bf16(((const unsigned short*)bv)[n]);
        } else {
            scale = dec_fp16(((const unsigned short*)sv)[n]);
            bias  = dec_fp16(((const unsigned short*)bv)[n]);
        }

        // D layout (m89-verified): col = ln (= n), row m = 16*tile + kq*4 + reg
        #pragma unroll
        for (int i = 0; i < 4; ++i) {
            #pragma unroll
            for (int r2 = 0; r2 < 4; ++r2) {
                const int    m   = 16 * i + kq * 4 + r2;
                const float  val = acc[i][r2] * scale + bias;
                const size_t o   = (size_t)m * OUT_F + n;
                if (xf == F_FP32)      ((float*)yv)[o] = val;
                else if (xf == F_BF16) ((unsigned short*)yv)[o] = enc_bf16_rne(val);
                else                   ((__half*)yv)[o] = __float2half(val);
            }
        }
    }
}

extern "C" void kernel_launch(void* const* d_in, const int* in_sizes, int n_in,
                              void* d_out, int out_size, void* d_ws, size_t ws_size,
                              hipStream_t stream) {
    unsigned short* xbf = (unsigned short*)d_ws;   // 512 KB: x as bf16
    prep_x<<<64, 256, 0, stream>>>(d_in[0], xbf);
    w8a16_main<<<OUT_F / NT, BLOCK, 0, stream>>>(d_in[0], (const int*)d_in[1],
                                                 d_in[2], d_in[3], d_out, xbf);
}